// Round 5
// baseline (6527.496 us; speedup 1.0000x reference)
//
#include <hip/hip_runtime.h>
#include <hip/hip_bf16.h>

#define VV 50257
#define DD 512
#define TT 1024
#define VPADN 50304   // 393*128
#define NB 16
#define WCB 128       // extra blocks doing W_out conversion concurrently
#define SLICE 132     // 128 + 4 pad: de-alias the four sl-slices across banks
#define HS (4*SLICE)

typedef __bf16 bf16;
typedef __attribute__((ext_vector_type(8))) __bf16 bf16x8;
typedef __attribute__((ext_vector_type(4))) __bf16 bf16x4;
typedef __attribute__((ext_vector_type(4))) float f32x4;
typedef __attribute__((ext_vector_type(4))) unsigned int u32x4;

__device__ __forceinline__ void gload_lds16(const void* g, void* l) {
  __builtin_amdgcn_global_load_lds(
      (__attribute__((address_space(1))) void*)(void*)g,
      (__attribute__((address_space(3))) void*)l, 16, 0, 0);
}

// ---------------- phase 1: sequential LSTM recurrence (blocks 0..15)
//                  + W_out f32->bf16 conversion (blocks 16..143, MODE 0 only) --------------
// MODE 0: real. MODE 3: re-run, polls final stamps (no wait), dummy tail.
// MODE 2: MODE 3 minus X-gather. MODE 1: no exchange (local-only h), compute floor.
template<int MODE>
__global__ __launch_bounds__(512) __attribute__((amdgpu_waves_per_eu(2, 2)))
void recur_t(
    const int* __restrict__ idx,
    const float* __restrict__ Wii, const float* __restrict__ Wif,
    const float* __restrict__ Wio, const float* __restrict__ Wig,
    const float* __restrict__ Whi, const float* __restrict__ Whf,
    const float* __restrict__ Who, const float* __restrict__ Whg,
    const float* __restrict__ bi, const float* __restrict__ bfv,
    const float* __restrict__ bo, const float* __restrict__ bg,
    const float* __restrict__ Wout,
    unsigned long long* __restrict__ Hpack, bf16* __restrict__ Hbf,
    bf16* __restrict__ Wbf, float* __restrict__ tail_dst) {
  __shared__ float hsh[2*HS];
  __shared__ int idxs[TT];
  const int b = blockIdx.x, tid = threadIdx.x;

  if (MODE == 0 && b >= NB) {   // ---- concurrent W_out conversion ----
    const int wb = b - NB;
    const size_t nch = (size_t)VPADN * DD / 4;
    for (size_t i = (size_t)wb * 512 + tid; i < nch; i += (size_t)WCB * 512) {
      size_t e = i << 2;
      bf16x4 o;
      if ((e >> 9) < VV) {
        f32x4 x = *(const f32x4*)&Wout[e];
        o[0] = (bf16)x[0]; o[1] = (bf16)x[1]; o[2] = (bf16)x[2]; o[3] = (bf16)x[3];
      } else {
        o[0] = o[1] = o[2] = o[3] = (bf16)0.f;
      }
      *(bf16x4*)&Wbf[e] = o;
    }
    return;
  }

  idxs[tid] = idx[tid];
  idxs[tid + 512] = idx[tid + 512];

  const int lane = tid & 63, w = tid >> 6;
  const int q = lane >> 4, gate = (lane >> 2) & 3, sl = lane & 3;
  const int hd = (b << 5) + (w << 2) + q;
  const float* Wg = (gate == 0) ? Whi : (gate == 1) ? Whf : (gate == 2) ? Who : Whg;

  f32x4 wv[32];
  {
    const float* wr_ = &Wg[(size_t)hd*DD + (sl << 7)];
    #pragma unroll
    for (int j = 0; j < 32; ++j) wv[j] = *(const f32x4*)(wr_ + 4*j);
  }
  #pragma unroll
  for (int j = 0; j < 32; ++j) asm volatile("" : "+v"(wv[j]));

  const float* Wx = (gate == 0) ? Wii : (gate == 1) ? Wif : (gate == 2) ? Wio : Wig;
  const float* bx = (gate == 0) ? bi : (gate == 1) ? bfv : (gate == 2) ? bo : bg;
  const float* wxp = &Wx[(size_t)hd * VV];
  const float bias = (sl == 0) ? bx[hd] : 0.f;
  const bool leader = (lane & 15) == 0;
  float c = 0.f;
  __syncthreads();   // idxs ready

  for (int t = 0; t < TT; ++t) {
    const int tok = idxs[t];
    const float xv = (sl == 0) ? ((MODE == 2 ? 0.f : wxp[tok]) + bias) : 0.f;

    float* hb = &hsh[(t & 1) * HS];
    if (MODE != 1) {
      if (t > 0) {
        if (tid < 256) {
          const unsigned long long* src = &Hpack[(size_t)(t-1)*DD + (tid << 1)];
          u32x4 v;
          for (;;) {
            asm volatile("global_load_dwordx4 %0, %1, off sc1\n\t"
                         "s_waitcnt vmcnt(0)"
                         : "=v"(v) : "v"(src) : "memory");
            if (v[1] == (unsigned)t && v[3] == (unsigned)t) break;
            __builtin_amdgcn_s_sleep(1);
          }
          const int d0 = tid << 1, s = d0 >> 7, off = d0 & 127;
          hb[s*SLICE + off]     = __uint_as_float(v[0]);
          hb[s*SLICE + off + 1] = __uint_as_float(v[2]);
        }
      } else {
        const int s = tid >> 7, off = tid & 127;
        hb[s*SLICE + off] = 0.f;
      }
    } else {
      if (t == 0) {
        const int s = tid >> 7, off = tid & 127;
        hsh[s*SLICE + off] = 0.f;
        hsh[HS + s*SLICE + off] = 0.f;
      }
    }
    __syncthreads();   // single barrier per step (hsh double-buffered)

    const float* hp = &hb[sl * SLICE];
    f32x4 a0 = {}, a1 = {}, a2 = {}, a3 = {};
    #pragma unroll
    for (int j = 0; j < 32; j += 4) {
      a0 += wv[j]     * *(const f32x4*)(hp + 4*j);
      a1 += wv[j + 1] * *(const f32x4*)(hp + 4*j + 4);
      a2 += wv[j + 2] * *(const f32x4*)(hp + 4*j + 8);
      a3 += wv[j + 3] * *(const f32x4*)(hp + 4*j + 12);
    }
    a0 += a1; a2 += a3; a0 += a2;
    float acc = a0[0] + a0[1] + a0[2] + a0[3];
    acc += __shfl_xor(acc, 1);
    acc += __shfl_xor(acc, 2);

    float pre = acc + xv;
    float e = __expf((gate == 3) ? -2.f * pre : -pre);
    float r = 1.f / (1.f + e);
    float act = (gate == 3) ? (2.f * r - 1.f) : r;

    int base = lane & 48;
    float fa = __shfl(act, base + 4);
    float oa = __shfl(act, base + 8);
    float ga = __shfl(act, base + 12);

    if (leader) {
      c = fa * c + act * ga;           // act == input gate activation
      float e2 = __expf(-2.f * c);
      float th = 2.f / (1.f + e2) - 1.f;
      float h = oa * th;
      unsigned long long pk =
          ((unsigned long long)(unsigned)(t + 1) << 32) | (unsigned long long)__float_as_uint(h);
      __hip_atomic_store(&Hpack[(size_t)t*DD + hd], pk, __ATOMIC_RELAXED,
                         __HIP_MEMORY_SCOPE_AGENT);
      Hbf[(size_t)t*DD + hd] = (bf16)h;
      if (MODE == 1) {  // local-only evolution: publish into next LDS buffer
        float* hn = &hsh[((t + 1) & 1) * HS];
        const int s = hd >> 7, off = hd & 127;
        hn[s*SLICE + off] = h;
      }
      if (t == TT - 1) { tail_dst[hd] = h; tail_dst[DD + hd] = c; }
    }
  }
}

// ---------------- phase 2: logits = Hbf[1024x512] @ Wbf^T[50304x512] + b_out ----------------
__global__ __launch_bounds__(256, 2) void gemm_kernel(
    const bf16* __restrict__ A, const bf16* __restrict__ B,
    const float* __restrict__ bout, float* __restrict__ Cout) {
  __shared__ bf16 As[128*32];
  __shared__ bf16 Bs[128*32];
  const int tid = threadIdx.x;
  const int n0 = blockIdx.x * 128, m0 = blockIdx.y * 128;
  const int w = tid >> 6, l = tid & 63;
  const int wr = w >> 1, wc = w & 1;
  f32x4 acc[4][4] = {};

  for (int k0 = 0; k0 < DD; k0 += 32) {
    #pragma unroll
    for (int c = 0; c < 2; ++c) {
      int j = c*256 + tid;
      int row = j >> 2, kc = (j & 3) << 3;
      gload_lds16(&A[(size_t)(m0 + row)*DD + k0 + kc], (char*)As + (c*4096 + w*1024));
      gload_lds16(&B[(size_t)(n0 + row)*DD + k0 + kc], (char*)Bs + (c*4096 + w*1024));
    }
    __syncthreads();
    bf16x8 af[4], bfr[4];
    #pragma unroll
    for (int mi = 0; mi < 4; ++mi)
      af[mi] = *(const bf16x8*)&As[(wr*64 + mi*16 + (l & 15))*32 + (l >> 4)*8];
    #pragma unroll
    for (int ni = 0; ni < 4; ++ni)
      bfr[ni] = *(const bf16x8*)&Bs[(wc*64 + ni*16 + (l & 15))*32 + (l >> 4)*8];
    #pragma unroll
    for (int mi = 0; mi < 4; ++mi)
      #pragma unroll
      for (int ni = 0; ni < 4; ++ni)
        acc[mi][ni] = __builtin_amdgcn_mfma_f32_16x16x32_bf16(af[mi], bfr[ni], acc[mi][ni], 0, 0, 0);
    __syncthreads();
  }

  #pragma unroll
  for (int mi = 0; mi < 4; ++mi) {
    int rbase = m0 + wr*64 + mi*16 + (l >> 4)*4;
    #pragma unroll
    for (int ni = 0; ni < 4; ++ni) {
      int col = n0 + wc*64 + ni*16 + (l & 15);
      if (col < VV) {
        float bb = bout[col];
        #pragma unroll
        for (int r = 0; r < 4; ++r)
          Cout[(size_t)(rbase + r)*VV + col] = acc[mi][ni][r] + bb;
      }
    }
  }
}

// ---------------- phase 3: in-place row log_softmax ----------------
__global__ __launch_bounds__(256) void lsm_kernel(float* __restrict__ logits) {
  const int t = blockIdx.x, tid = threadIdx.x;
  float* row = logits + (size_t)t*VV;
  float m = -INFINITY, s = 0.f;
  for (int v = tid; v < VV; v += 256) {
    float x = row[v];
    float nm = fmaxf(m, x);
    s = s*expf(m - nm) + expf(x - nm);
    m = nm;
  }
  #pragma unroll
  for (int mask = 1; mask < 64; mask <<= 1) {
    float om = __shfl_xor(m, mask);
    float os = __shfl_xor(s, mask);
    float nm = fmaxf(m, om);
    s = s*expf(m - nm) + os*expf(om - nm);
    m = nm;
  }
  __shared__ float sm[4], ss[4], lse_sh;
  int wv = tid >> 6;
  if ((tid & 63) == 0) { sm[wv] = m; ss[wv] = s; }
  __syncthreads();
  if (tid == 0) {
    float M = sm[0], S = ss[0];
    for (int i2 = 1; i2 < 4; ++i2) {
      float nm = fmaxf(M, sm[i2]);
      S = S*expf(M - nm) + ss[i2]*expf(sm[i2] - nm);
      M = nm;
    }
    lse_sh = M + logf(S);
  }
  __syncthreads();
  float lse = lse_sh;
  for (int v = tid; v < VV; v += 256)
    row[v] -= lse;
}

extern "C" void kernel_launch(void* const* d_in, const int* in_sizes, int n_in,
                              void* d_out, int out_size, void* d_ws, size_t ws_size,
                              hipStream_t stream) {
  const int*   idx  = (const int*)d_in[0];
  const float* Wii  = (const float*)d_in[1];
  const float* Wif  = (const float*)d_in[2];
  const float* Wio  = (const float*)d_in[3];
  const float* Wig  = (const float*)d_in[4];
  const float* Whi  = (const float*)d_in[5];
  const float* Whf  = (const float*)d_in[6];
  const float* Who  = (const float*)d_in[7];
  const float* Whg  = (const float*)d_in[8];
  const float* bi   = (const float*)d_in[9];
  const float* bfv  = (const float*)d_in[10];
  const float* bo   = (const float*)d_in[11];
  const float* bg   = (const float*)d_in[12];
  const float* Wout = (const float*)d_in[13];
  const float* bout = (const float*)d_in[14];
  float* out = (float*)d_out;

  // ws layout:
  //   [0, 51511296)        : Wbf (50304*512 bf16)
  //   [51511296, +4194304) : Hpack (TT*DD u64: stamp<<32 | h bits)
  //   [55705600, +1048576) : Hbf (TT*DD bf16)
  //   [59000000, +4096)    : tailD (ablation-variant dummy tail)
  char* ws = (char*)d_ws;
  bf16*  Wbf  = (bf16*)ws;
  unsigned long long* Hpack = (unsigned long long*)(ws + 51511296);
  bf16*  Hbf  = (bf16*)(ws + 55705600);
  float* tailD = (float*)(ws + 59000000);

  hipMemsetAsync(Hpack, 0, (size_t)TT*DD*8, stream);   // fresh stamps every launch
  recur_t<0><<<NB + WCB, 512, 0, stream>>>(
      idx, Wii, Wif, Wio, Wig, Whi, Whf, Who, Whg, bi, bfv, bo, bg, Wout,
      Hpack, Hbf, Wbf, out + (size_t)TT*VV);
  gemm_kernel<<<dim3(393, 8), 256, 0, stream>>>(Hbf, Wbf, bout, out);
  lsm_kernel<<<TT, 256, 0, stream>>>(out);

  // ---- diagnostic ablations (dummy outputs; stamps final -> no waiting) ----
  recur_t<3><<<NB, 512, 0, stream>>>(   // full loop, no producer-wait
      idx, Wii, Wif, Wio, Wig, Whi, Whf, Who, Whg, bi, bfv, bo, bg, Wout,
      Hpack, Hbf, Wbf, tailD);
  recur_t<2><<<NB, 512, 0, stream>>>(   // minus X-gather
      idx, Wii, Wif, Wio, Wig, Whi, Whf, Who, Whg, bi, bfv, bo, bg, Wout,
      Hpack, Hbf, Wbf, tailD);
  recur_t<1><<<NB, 512, 0, stream>>>(   // no exchange: compute floor
      idx, Wii, Wif, Wio, Wig, Whi, Whf, Who, Whg, bi, bfv, bo, bg, Wout,
      Hpack, Hbf, Wbf, tailD);
}

// Round 6
// 2244.607 us; speedup vs baseline: 2.9081x; 2.9081x over previous
//
#include <hip/hip_runtime.h>
#include <hip/hip_bf16.h>

#define VV 50257
#define DD 512
#define TT 1024
#define VPADN 50304   // 393*128
#define NBR 32        // recurrence blocks, 16 h-dims each
#define WCB 128       // extra blocks doing W_out conversion concurrently

typedef __bf16 bf16;
typedef __attribute__((ext_vector_type(8))) __bf16 bf16x8;
typedef __attribute__((ext_vector_type(4))) __bf16 bf16x4;
typedef __attribute__((ext_vector_type(4))) float f32x4;
typedef __attribute__((ext_vector_type(4))) unsigned int u32x4;

__device__ __forceinline__ void gload_lds16(const void* g, void* l) {
  __builtin_amdgcn_global_load_lds(
      (__attribute__((address_space(1))) void*)(void*)g,
      (__attribute__((address_space(3))) void*)l, 16, 0, 0);
}

// ---------------- phase 1: sequential LSTM recurrence (blocks 0..31)
//                  + W_out f32->bf16 conversion (blocks 32..159, concurrent) --------------
// Block b<32 owns h-dims [b*16, b*16+16) -> 64 gate-rows.
// Thread: r = tid>>3 (row), s = tid&7 (col slot, 64 cols each).
// Row r: gate g = r&3, local dim dlg = r>>2, hd = b*16 + dlg.
// The 4 gate-rows of one dim = 32 consecutive tids -> same wave: shfl combine, no LDS.
// Weights: 15/16 in LDS (transposed [k][tid] f32x4, conflict-free), 1/16 in regs.
// h exchange: u64 (stamp<<32|bits) per dim via L3, 256 pollers x dwordx4 sc1.
__global__ __launch_bounds__(512) void recur_fused_kernel(
    const int* __restrict__ idx,
    const float* __restrict__ Wii, const float* __restrict__ Wif,
    const float* __restrict__ Wio, const float* __restrict__ Wig,
    const float* __restrict__ Whi, const float* __restrict__ Whf,
    const float* __restrict__ Who, const float* __restrict__ Whg,
    const float* __restrict__ bi, const float* __restrict__ bfv,
    const float* __restrict__ bo, const float* __restrict__ bg,
    const float* __restrict__ Wout,
    unsigned long long* __restrict__ Hpack, bf16* __restrict__ Hbf,
    bf16* __restrict__ Wbf, float* __restrict__ out_tail) {
  __shared__ f32x4 wlds[15][512];    // 122880 B
  __shared__ f32x4 hsh[2][16][8];    // 4096 B   (chunk s of h at [buf][k][s])
  const int b = blockIdx.x, tid = threadIdx.x;

  if (b >= NBR) {            // ---- concurrent W_out conversion ----
    const int wb = b - NBR;
    const size_t nch = (size_t)VPADN * DD / 4;
    for (size_t i = (size_t)wb * 512 + tid; i < nch; i += (size_t)WCB * 512) {
      size_t e = i << 2;
      bf16x4 o;
      if ((e >> 9) < VV) {
        f32x4 x = *(const f32x4*)&Wout[e];
        o[0] = (bf16)x[0]; o[1] = (bf16)x[1]; o[2] = (bf16)x[2]; o[3] = (bf16)x[3];
      } else {
        o[0] = o[1] = o[2] = o[3] = (bf16)0.f;
      }
      *(bf16x4*)&Wbf[e] = o;
    }
    return;
  }

  const int r = tid >> 3, s = tid & 7;
  const int g = r & 3, dlg = r >> 2;
  const int hd = (b << 4) + dlg;
  const float* Wg = (g == 0) ? Whi : (g == 1) ? Whf : (g == 2) ? Who : Whg;

  // stage weight row slice W_g[hd][s*64 .. s*64+64): 15 chunks to LDS, last in regs
  f32x4 wreg;
  {
    const float* src = &Wg[(size_t)hd*DD + (s << 6)];
    #pragma unroll
    for (int k = 0; k < 15; ++k) wlds[k][tid] = *(const f32x4*)(src + 4*k);
    wreg = *(const f32x4*)(src + 60);
    asm volatile("" : "+v"(wreg));
  }
  { // zero both h buffers: 1024 floats, 2 per thread
    float2* hz = (float2*)hsh;
    hz[tid] = float2{0.f, 0.f};
  }

  const float* Wx = (g == 0) ? Wii : (g == 1) ? Wif : (g == 2) ? Wio : Wig;
  const float* bx = (g == 0) ? bi : (g == 1) ? bfv : (g == 2) ? bo : bg;
  const float* wxp = &Wx[(size_t)hd * VV];
  const float bias = (s == 0) ? bx[hd] : 0.f;
  const bool cupd = ((tid & 31) == 0);   // s==0 && g==0: c/h updater for dim hd
  float c = 0.f;
  __syncthreads();

  for (int t = 0; t < TT; ++t) {
    const int tok = idx[t];
    // gate-input gather from W_i* column (independent of h -> overlaps poll)
    const float xv = (s == 0) ? (wxp[tok] + bias) : 0.f;

    f32x4 (*hb)[8] = hsh[t & 1];
    if (t > 0 && tid < 256) {
      const unsigned long long* src = &Hpack[(size_t)(t-1)*DD + (tid << 1)];
      u32x4 v;
      for (;;) {
        asm volatile("global_load_dwordx4 %0, %1, off sc1\n\t"
                     "s_waitcnt vmcnt(0)"
                     : "=v"(v) : "v"(src) : "memory");
        if (v[1] == (unsigned)t && v[3] == (unsigned)t) break;
        __builtin_amdgcn_s_sleep(1);
      }
      const int d0 = tid << 1;
      const int kk = (d0 & 63) >> 2, sc = d0 >> 6, e = d0 & 3;
      float* hf = (float*)hb;
      *(float2*)&hf[(((kk << 3) + sc) << 2) + e] =
          float2{__uint_as_float(v[0]), __uint_as_float(v[2])};
    }
    __syncthreads();   // single barrier per step (hsh double-buffered)

    const f32x4* hp = &hb[0][s];   // stride 8 f32x4 between k-chunks
    f32x4 a0 = {}, a1 = {}, a2 = {}, a3 = {};
    #pragma unroll
    for (int k = 0; k < 12; k += 4) {
      a0 += wlds[k    ][tid] * hp[(k    ) << 3];
      a1 += wlds[k + 1][tid] * hp[(k + 1) << 3];
      a2 += wlds[k + 2][tid] * hp[(k + 2) << 3];
      a3 += wlds[k + 3][tid] * hp[(k + 3) << 3];
    }
    a0 += wlds[12][tid] * hp[96];
    a1 += wlds[13][tid] * hp[104];
    a2 += wlds[14][tid] * hp[112];
    a3 += wreg * hp[120];
    a0 += a1; a2 += a3; a0 += a2;
    float acc = a0[0] + a0[1] + a0[2] + a0[3];
    acc += __shfl_xor(acc, 1);
    acc += __shfl_xor(acc, 2);
    acc += __shfl_xor(acc, 4);

    // per-row activation on the s==0 lane of each gate-row
    float pre = acc + xv;
    float e1 = __expf((g == 3) ? -2.f * pre : -pre);
    float rr = 1.f / (1.f + e1);
    float act = (g == 3) ? (2.f * rr - 1.f) : rr;

    const int half = tid & 32;                 // which dim within this wave
    float fa = __shfl(act, half + 8);
    float oa = __shfl(act, half + 16);
    float ga = __shfl(act, half + 24);

    if (cupd) {
      c = fa * c + act * ga;                   // act == input-gate activation
      float e2 = __expf(-2.f * c);
      float th = 2.f / (1.f + e2) - 1.f;
      float h = oa * th;
      unsigned long long pk =
          ((unsigned long long)(unsigned)(t + 1) << 32) | (unsigned long long)__float_as_uint(h);
      __hip_atomic_store(&Hpack[(size_t)t*DD + hd], pk, __ATOMIC_RELAXED,
                         __HIP_MEMORY_SCOPE_AGENT);
      Hbf[(size_t)t*DD + hd] = (bf16)h;
      if (t == TT - 1) { out_tail[hd] = h; out_tail[DD + hd] = c; }
    }
  }
}

// ---------------- phase 2: logits = Hbf[1024x512] @ Wbf^T[50304x512] + b_out ----------------
__global__ __launch_bounds__(256, 2) void gemm_kernel(
    const bf16* __restrict__ A, const bf16* __restrict__ B,
    const float* __restrict__ bout, float* __restrict__ Cout) {
  __shared__ bf16 As[128*32];
  __shared__ bf16 Bs[128*32];
  const int tid = threadIdx.x;
  const int n0 = blockIdx.x * 128, m0 = blockIdx.y * 128;
  const int w = tid >> 6, l = tid & 63;
  const int wr = w >> 1, wc = w & 1;
  f32x4 acc[4][4] = {};

  for (int k0 = 0; k0 < DD; k0 += 32) {
    #pragma unroll
    for (int c = 0; c < 2; ++c) {
      int j = c*256 + tid;
      int row = j >> 2, kc = (j & 3) << 3;
      gload_lds16(&A[(size_t)(m0 + row)*DD + k0 + kc], (char*)As + (c*4096 + w*1024));
      gload_lds16(&B[(size_t)(n0 + row)*DD + k0 + kc], (char*)Bs + (c*4096 + w*1024));
    }
    __syncthreads();
    bf16x8 af[4], bfr[4];
    #pragma unroll
    for (int mi = 0; mi < 4; ++mi)
      af[mi] = *(const bf16x8*)&As[(wr*64 + mi*16 + (l & 15))*32 + (l >> 4)*8];
    #pragma unroll
    for (int ni = 0; ni < 4; ++ni)
      bfr[ni] = *(const bf16x8*)&Bs[(wc*64 + ni*16 + (l & 15))*32 + (l >> 4)*8];
    #pragma unroll
    for (int mi = 0; mi < 4; ++mi)
      #pragma unroll
      for (int ni = 0; ni < 4; ++ni)
        acc[mi][ni] = __builtin_amdgcn_mfma_f32_16x16x32_bf16(af[mi], bfr[ni], acc[mi][ni], 0, 0, 0);
    __syncthreads();
  }

  #pragma unroll
  for (int mi = 0; mi < 4; ++mi) {
    int rbase = m0 + wr*64 + mi*16 + (l >> 4)*4;
    #pragma unroll
    for (int ni = 0; ni < 4; ++ni) {
      int col = n0 + wc*64 + ni*16 + (l & 15);
      if (col < VV) {
        float bb = bout[col];
        #pragma unroll
        for (int r = 0; r < 4; ++r)
          Cout[(size_t)(rbase + r)*VV + col] = acc[mi][ni][r] + bb;
      }
    }
  }
}

// ---------------- phase 3: in-place row log_softmax ----------------
__global__ __launch_bounds__(256) void lsm_kernel(float* __restrict__ logits) {
  const int t = blockIdx.x, tid = threadIdx.x;
  float* row = logits + (size_t)t*VV;
  float m = -INFINITY, s = 0.f;
  for (int v = tid; v < VV; v += 256) {
    float x = row[v];
    float nm = fmaxf(m, x);
    s = s*expf(m - nm) + expf(x - nm);
    m = nm;
  }
  #pragma unroll
  for (int mask = 1; mask < 64; mask <<= 1) {
    float om = __shfl_xor(m, mask);
    float os = __shfl_xor(s, mask);
    float nm = fmaxf(m, om);
    s = s*expf(m - nm) + os*expf(om - nm);
    m = nm;
  }
  __shared__ float sm[4], ss[4], lse_sh;
  int wv = tid >> 6;
  if ((tid & 63) == 0) { sm[wv] = m; ss[wv] = s; }
  __syncthreads();
  if (tid == 0) {
    float M = sm[0], S = ss[0];
    for (int i2 = 1; i2 < 4; ++i2) {
      float nm = fmaxf(M, sm[i2]);
      S = S*expf(M - nm) + ss[i2]*expf(sm[i2] - nm);
      M = nm;
    }
    lse_sh = M + logf(S);
  }
  __syncthreads();
  float lse = lse_sh;
  for (int v = tid; v < VV; v += 256)
    row[v] -= lse;
}

extern "C" void kernel_launch(void* const* d_in, const int* in_sizes, int n_in,
                              void* d_out, int out_size, void* d_ws, size_t ws_size,
                              hipStream_t stream) {
  const int*   idx  = (const int*)d_in[0];
  const float* Wii  = (const float*)d_in[1];
  const float* Wif  = (const float*)d_in[2];
  const float* Wio  = (const float*)d_in[3];
  const float* Wig  = (const float*)d_in[4];
  const float* Whi  = (const float*)d_in[5];
  const float* Whf  = (const float*)d_in[6];
  const float* Who  = (const float*)d_in[7];
  const float* Whg  = (const float*)d_in[8];
  const float* bi   = (const float*)d_in[9];
  const float* bfv  = (const float*)d_in[10];
  const float* bo   = (const float*)d_in[11];
  const float* bg   = (const float*)d_in[12];
  const float* Wout = (const float*)d_in[13];
  const float* bout = (const float*)d_in[14];
  float* out = (float*)d_out;

  // ws layout:
  //   [0, 51511296)        : Wbf (50304*512 bf16)
  //   [51511296, +4194304) : Hpack (TT*DD u64: stamp<<32 | h bits)
  //   [55705600, +1048576) : Hbf (TT*DD bf16)
  char* ws = (char*)d_ws;
  bf16*  Wbf  = (bf16*)ws;
  unsigned long long* Hpack = (unsigned long long*)(ws + 51511296);
  bf16*  Hbf  = (bf16*)(ws + 55705600);

  hipMemsetAsync(Hpack, 0, (size_t)TT*DD*8, stream);   // fresh stamps every launch
  recur_fused_kernel<<<NBR + WCB, 512, 0, stream>>>(
      idx, Wii, Wif, Wio, Wig, Whi, Whf, Who, Whg, bi, bfv, bo, bg, Wout,
      Hpack, Hbf, Wbf, out + (size_t)TT*VV);
  gemm_kernel<<<dim3(393, 8), 256, 0, stream>>>(Hbf, Wbf, bout, out);
  lsm_kernel<<<TT, 256, 0, stream>>>(out);
}